// Round 2
// baseline (882.255 us; speedup 1.0000x reference)
//
#include <hip/hip_runtime.h>
#include <float.h>
#include <math.h>

#define DIM 512
#define VDIM 512
#define ROWS_PER_WAVE 32
#define WAVES_PER_BLOCK 4
#define BATCH 4

__device__ __forceinline__ float dot8(const float4& a0, const float4& a1,
                                      const float4& q0, const float4& q1) {
    return a0.x*q0.x + a0.y*q0.y + a0.z*q0.z + a0.w*q0.w
         + a1.x*q1.x + a1.y*q1.y + a1.z*q1.z + a1.w*q1.w;
}

__device__ __forceinline__ float waveReduce(float d) {
    #pragma unroll
    for (int off = 32; off > 0; off >>= 1)
        d += __shfl_xor(d, off, 64);
    return d;
}

// Kernel A: one wave per 32-row chunk, processed in batches of 4 rows so the
// wave keeps 8 float4 loads in flight (memory-level parallelism — the R0
// version had only 2 and was latency-bound at ~1.4 TB/s). The 4 butterfly
// reduce chains per batch are independent, so their shfl latency overlaps.
__global__ __launch_bounds__(256) void logits_partials(
    const float* __restrict__ query,
    const float* __restrict__ keys,
    int n,
    float* __restrict__ pmax,
    float* __restrict__ psum,
    int*   __restrict__ pidx)
{
    const int lane = threadIdx.x & 63;
    const int wave = threadIdx.x >> 6;

    const float4 q0 = *(const float4*)(query + lane * 8);
    const float4 q1 = *(const float4*)(query + lane * 8 + 4);

    const int waveId = blockIdx.x * WAVES_PER_BLOCK + wave;
    const int row0   = waveId * ROWS_PER_WAVE;

    float m  = -FLT_MAX;
    float s  = 0.0f;
    int   mi = -1;

    if (row0 + ROWS_PER_WAVE <= n) {
        // Fast path: full chunk, no per-row guards, pipelineable.
        #pragma unroll
        for (int g = 0; g < ROWS_PER_WAVE; g += BATCH) {
            const float* kp = keys + (size_t)(row0 + g) * DIM + lane * 8;
            // 8 independent 16B loads — all issued before any use.
            const float4 a0 = *(const float4*)(kp);
            const float4 a1 = *(const float4*)(kp + 4);
            const float4 b0 = *(const float4*)(kp + DIM);
            const float4 b1 = *(const float4*)(kp + DIM + 4);
            const float4 c0 = *(const float4*)(kp + 2*DIM);
            const float4 c1 = *(const float4*)(kp + 2*DIM + 4);
            const float4 e0 = *(const float4*)(kp + 3*DIM);
            const float4 e1 = *(const float4*)(kp + 3*DIM + 4);

            float d0 = dot8(a0, a1, q0, q1);
            float d1 = dot8(b0, b1, q0, q1);
            float d2 = dot8(c0, c1, q0, q1);
            float d3 = dot8(e0, e1, q0, q1);
            // 4 independent butterfly chains (ILP hides ds-op latency).
            #pragma unroll
            for (int off = 32; off > 0; off >>= 1) {
                d0 += __shfl_xor(d0, off, 64);
                d1 += __shfl_xor(d1, off, 64);
                d2 += __shfl_xor(d2, off, 64);
                d3 += __shfl_xor(d3, off, 64);
            }
            // Batched online-softmax update (wave-uniform values).
            const float bm = fmaxf(fmaxf(d0, d1), fmaxf(d2, d3));
            if (bm > m) {
                s *= __expf(m - bm);   // m=-FLT_MAX first iter -> exp(-inf)=0
                m = bm;
                mi = (d0 == bm) ? row0 + g
                   : (d1 == bm) ? row0 + g + 1
                   : (d2 == bm) ? row0 + g + 2
                                : row0 + g + 3;
            }
            s += __expf(d0 - m) + __expf(d1 - m) + __expf(d2 - m) + __expf(d3 - m);
        }
    } else {
        for (int r = 0; r < ROWS_PER_WAVE; ++r) {
            const int row = row0 + r;
            if (row >= n) break;
            const float* kp = keys + (size_t)row * DIM + lane * 8;
            const float4 k0 = *(const float4*)kp;
            const float4 k1 = *(const float4*)(kp + 4);
            float d = waveReduce(dot8(k0, k1, q0, q1));
            if (d > m) { s = s * __expf(m - d) + 1.0f; m = d; mi = row; }
            else       { s += __expf(d - m); }
        }
    }

    __shared__ float sm[WAVES_PER_BLOCK];
    __shared__ float ss[WAVES_PER_BLOCK];
    __shared__ int   si[WAVES_PER_BLOCK];
    if (lane == 0) { sm[wave] = m; ss[wave] = s; si[wave] = mi; }
    __syncthreads();
    if (threadIdx.x == 0) {
        float M = sm[0]; int I = si[0];
        #pragma unroll
        for (int w = 1; w < WAVES_PER_BLOCK; ++w)
            if (sm[w] > M) { M = sm[w]; I = si[w]; }
        float S = 0.0f;
        #pragma unroll
        for (int w = 0; w < WAVES_PER_BLOCK; ++w)
            S += ss[w] * __expf(sm[w] - M);
        pmax[blockIdx.x] = M;
        psum[blockIdx.x] = S;
        pidx[blockIdx.x] = I;
    }
}

// Kernel B: single block. Reduce per-block partials -> global max/argmax/denom,
// then out = values[argmax] / denom.
__global__ __launch_bounds__(512) void finalize(
    const float* __restrict__ pmax,
    const float* __restrict__ psum,
    const int*   __restrict__ pidx,
    int nb,
    const float* __restrict__ values,
    float* __restrict__ out)
{
    __shared__ float sm[512];
    __shared__ int   si[512];
    __shared__ float ssum[512];

    const int tid = threadIdx.x;

    float m = -FLT_MAX; int mi = -1;
    for (int b = tid; b < nb; b += 512) {
        const float mb = pmax[b];
        if (mb > m) { m = mb; mi = pidx[b]; }
    }
    sm[tid] = m; si[tid] = mi;
    __syncthreads();
    #pragma unroll
    for (int off = 256; off > 0; off >>= 1) {
        if (tid < off) {
            if (sm[tid + off] > sm[tid]) { sm[tid] = sm[tid + off]; si[tid] = si[tid + off]; }
        }
        __syncthreads();
    }
    const float M = sm[0];
    const int   I = si[0];

    float s = 0.0f;
    for (int b = tid; b < nb; b += 512)
        s += psum[b] * __expf(pmax[b] - M);
    ssum[tid] = s;
    __syncthreads();
    #pragma unroll
    for (int off = 256; off > 0; off >>= 1) {
        if (tid < off) ssum[tid] += ssum[tid + off];
        __syncthreads();
    }
    const float inv = 1.0f / ssum[0];

    for (int v = tid; v < VDIM; v += 512)
        out[v] = values[(size_t)I * VDIM + v] * inv;
}

extern "C" void kernel_launch(void* const* d_in, const int* in_sizes, int n_in,
                              void* d_out, int out_size, void* d_ws, size_t ws_size,
                              hipStream_t stream) {
    const float* query  = (const float*)d_in[0];
    const float* keys   = (const float*)d_in[1];
    const float* values = (const float*)d_in[2];
    float* out = (float*)d_out;

    const int n = in_sizes[1] / DIM;  // 262144

    const int rowsPerBlock = ROWS_PER_WAVE * WAVES_PER_BLOCK;  // 128
    const int nb = (n + rowsPerBlock - 1) / rowsPerBlock;      // 2048

    float* pmax = (float*)d_ws;
    float* psum = pmax + nb;
    int*   pidx = (int*)(psum + nb);

    logits_partials<<<nb, 256, 0, stream>>>(query, keys, n, pmax, psum, pidx);
    finalize<<<1, 512, 0, stream>>>(pmax, psum, pidx, nb, values, out);
}